// Round 9
// baseline (4547.893 us; speedup 1.0000x reference)
//
#include <hip/hip_runtime.h>
#include <hip/hip_bf16.h>

#define DD 128            // codebook dim

__global__ void plant_diag(float val, float* out) {
    if (threadIdx.x == 0 && blockIdx.x == 0) out[0] = val;
}

__global__ void zero_acc(double* acc) {
    if (threadIdx.x == 0 && blockIdx.x == 0) { acc[0] = 0.0; acc[1] = 0.0; }
}

// ---------------- silu mimicking np: x * (1/(1+exp(-x))), each op f32-rounded ----------------
__device__ __forceinline__ float silu_np(float x) {
    float e = (float)exp(-(double)x);   // correctly-rounded f32 exp
    float u = 1.0f + e;
    float v = 1.0f / u;
    return x * v;
}

// ---------------- gemm_rows: C = act(A@W + b), np/BLAS-faithful sequential chains ----------------
// 8 rows per block-row; A read via wave-uniform loads (scalar pipe), W coalesced vector loads.
// Each C[m,n] = ascending-k fmaf chain (bit-identical to round-8 gemm_seq).
template <bool SILU>
__global__ __launch_bounds__(256) void gemm_rows(const float* __restrict__ A,
                                                 const float* __restrict__ W,
                                                 const float* __restrict__ bias,
                                                 float* __restrict__ C,
                                                 int M, int N, int K) {
    const int t = threadIdx.x;
    const int n = blockIdx.x * 256 + t;
    const int m0 = blockIdx.y * 8;
    if (n >= N) return;

    const float* Ar[8];
#pragma unroll
    for (int r = 0; r < 8; ++r) {
        int m = m0 + r; if (m >= M) m = M - 1;
        Ar[r] = A + (size_t)m * K;
    }
    const float* Wn = W + n;

    float acc[8];
#pragma unroll
    for (int r = 0; r < 8; ++r) acc[r] = 0.0f;

    int k = 0;
    for (; k + 8 <= K; k += 8) {
        float w[8];
#pragma unroll
        for (int j = 0; j < 8; ++j) w[j] = Wn[(size_t)(k + j) * N];
#pragma unroll
        for (int r = 0; r < 8; ++r) {
#pragma unroll
            for (int j = 0; j < 8; ++j)
                acc[r] = fmaf(Ar[r][k + j], w[j], acc[r]);   // ascending k per output
        }
    }
    for (; k < K; ++k) {
        float w = Wn[(size_t)k * N];
#pragma unroll
        for (int r = 0; r < 8; ++r) acc[r] = fmaf(Ar[r][k], w, acc[r]);
    }

    const float b = bias[n];
    const int rows = (M - m0 < 8) ? (M - m0) : 8;
    for (int r = 0; r < rows; ++r) {
        float x = acc[r] + b;
        if (SILU) x = silu_np(x);
        C[(size_t)(m0 + r) * N + n] = x;
    }
}

// ---------------- np pairwise sum-of-squares over 128 (8-acc unrolled) ----------------
__device__ __forceinline__ float pairwise128_sq(const float* __restrict__ x, int stride) {
    float r0 = x[0*stride]*x[0*stride], r1 = x[1*stride]*x[1*stride],
          r2 = x[2*stride]*x[2*stride], r3 = x[3*stride]*x[3*stride],
          r4 = x[4*stride]*x[4*stride], r5 = x[5*stride]*x[5*stride],
          r6 = x[6*stride]*x[6*stride], r7 = x[7*stride]*x[7*stride];
    for (int i = 8; i < 128; i += 8) {
        r0 += x[(i+0)*stride]*x[(i+0)*stride];
        r1 += x[(i+1)*stride]*x[(i+1)*stride];
        r2 += x[(i+2)*stride]*x[(i+2)*stride];
        r3 += x[(i+3)*stride]*x[(i+3)*stride];
        r4 += x[(i+4)*stride]*x[(i+4)*stride];
        r5 += x[(i+5)*stride]*x[(i+5)*stride];
        r6 += x[(i+6)*stride]*x[(i+6)*stride];
        r7 += x[(i+7)*stride]*x[(i+7)*stride];
    }
    return ((r0 + r1) + (r2 + r3)) + ((r4 + r5) + (r6 + r7));
}

__global__ void code_t2(const float* __restrict__ cb, float* __restrict__ t2, int K) {
    int k = blockIdx.x * 256 + threadIdx.x;
    if (k >= K) return;
    t2[k] = pairwise128_sq(cb + (size_t)k * DD, 1);
}

// ---------------- vq_np2: np-f32-faithful VQ argmin, register-tiled ----------------
// Block: 64 rows x full K (64-code panels). 256 thr = 16 row-groups x 16 code-groups.
// Lane tile: 4 rows x 4 codes. Per d: 2x b128 LDS reads -> 16 fmaf (VALU-bound).
// Exactness: per (row,code) dot = ascending-d fmaf chain within its panel (= round 8);
// dist = (t1 + t2[c]) - 2*dot, f32 each op; argmin = global first-min.
__global__ __launch_bounds__(256) void vq_np2(const float* __restrict__ lat,
                                              const float* __restrict__ cb,
                                              const float* __restrict__ t2,
                                              int* __restrict__ indices,
                                              double* __restrict__ acc, int K,
                                              int rows_total) {
    __shared__ __align__(16) float Ls[128][68];   // [d][row]
    __shared__ __align__(16) float Cs[128][68];   // [d][code]
    __shared__ float T1s[64];
    __shared__ float T2s[64];
    __shared__ float bvs[64][17];
    __shared__ int   bks[64][17];
    __shared__ float bvf[64];

    const int t = threadIdx.x;
    const int tx = t & 15, ty = t >> 4;
    const int r0 = blockIdx.x * 64;

    // stage latent rows transposed
#pragma unroll
    for (int it = 0; it < 32; ++it) {
        int i = t + 256 * it;
        int row = i >> 7, d = i & 127;
        int rr = r0 + row; if (rr >= rows_total) rr = rows_total - 1;
        Ls[d][row] = lat[(size_t)rr * DD + d];
    }
    __syncthreads();
    if (t < 64) T1s[t] = pairwise128_sq(&Ls[0][t], 68);   // np-pairwise ||l||^2 per row

    float bestv[4]; int bestk[4];
#pragma unroll
    for (int r = 0; r < 4; ++r) { bestv[r] = 3.4e38f; bestk[r] = 0; }

    for (int k0 = 0; k0 < K; k0 += 64) {
        __syncthreads();
        // stage 64 codes transposed: consecutive lanes -> consecutive codes (conflict-free)
#pragma unroll
        for (int it = 0; it < 8; ++it) {
            int g = t + 256 * it;
            int c = g & 63, dq = g >> 6;            // dq 0..31
            int cc = k0 + c; if (cc >= K) cc = K - 1;
            const float4 v = *(const float4*)(cb + (size_t)cc * DD + 4 * dq);
            Cs[4*dq+0][c] = v.x; Cs[4*dq+1][c] = v.y;
            Cs[4*dq+2][c] = v.z; Cs[4*dq+3][c] = v.w;
        }
        if (t < 64) { int cc = k0 + t; if (cc >= K) cc = K - 1; T2s[t] = t2[cc]; }
        __syncthreads();

        float s[4][4];
#pragma unroll
        for (int r = 0; r < 4; ++r)
#pragma unroll
            for (int j = 0; j < 4; ++j) s[r][j] = 0.0f;

        for (int d = 0; d < 128; ++d) {           // ascending d: exact sgemm chain order
            const float4 a4 = *(const float4*)&Ls[d][4 * tx];
            const float4 c4 = *(const float4*)&Cs[d][4 * ty];
            const float av[4] = {a4.x, a4.y, a4.z, a4.w};
            const float cv[4] = {c4.x, c4.y, c4.z, c4.w};
#pragma unroll
            for (int r = 0; r < 4; ++r)
#pragma unroll
                for (int j = 0; j < 4; ++j)
                    s[r][j] = fmaf(av[r], cv[j], s[r][j]);
        }

#pragma unroll
        for (int r = 0; r < 4; ++r) {
            const float t1 = T1s[4 * tx + r];
#pragma unroll
            for (int j = 0; j < 4; ++j) {        // ascending j = ascending code
                int kc = k0 + 4 * ty + j;
                float dist = (t1 + T2s[4 * ty + j]) - 2.0f * s[r][j];
                if (kc < K && dist < bestv[r]) { bestv[r] = dist; bestk[r] = kc; }
            }
        }
    }

#pragma unroll
    for (int r = 0; r < 4; ++r) {
        bvs[4 * tx + r][ty] = bestv[r];
        bks[4 * tx + r][ty] = bestk[r];
    }
    __syncthreads();
    if (t < 64) {
        float bv = bvs[t][0]; int bk = bks[t][0];
        for (int j = 1; j < 16; ++j) {           // ascending ty = ascending code blocks
            float v = bvs[t][j]; int k = bks[t][j];
            if (v < bv || (v == bv && k < bk)) { bv = v; bk = k; }
        }
        bool valid = (r0 + t) < rows_total;
        if (valid) indices[r0 + t] = bk;
        bvf[t] = valid ? bv : 0.0f;
    }
    __syncthreads();
    if (t == 0) {
        double ssum = 0.0;
        for (int r = 0; r < 64; ++r) ssum += (double)bvf[r];
        atomicAdd(acc, ssum);
    }
}

// ---------------- Q gather ----------------
__global__ void q_gather(const int* __restrict__ idx, const float* __restrict__ cb,
                         float* __restrict__ Q, int count, int nlat) {
    int gid = blockIdx.x * 256 + threadIdx.x;
    if (gid >= count) return;
    int m = gid >> 11;            // / LAT (2048)
    int j = gid & 2047;
    int code = idx[m * nlat + (j >> 7)];
    Q[gid] = cb[((size_t)code << 7) + (j & 127)];
}

// ---------------- recon loss + f32 write ----------------
__global__ __launch_bounds__(256) void recon_out(const float* __restrict__ recon,
                                                 const float* __restrict__ actions,
                                                 float* __restrict__ out,
                                                 double* __restrict__ acc, int count) {
    int gid = blockIdx.x * 256 + threadIdx.x;
    double sq = 0.0;
    if (gid < count) {
        float rv = recon[gid];
        float av = actions[gid];
        double diff = (double)rv - (double)av;
        out[gid] = rv;
        sq = diff * diff;
    }
    __shared__ double red[256];
    red[threadIdx.x] = sq;
    __syncthreads();
    for (int s = 128; s > 0; s >>= 1) {
        if (threadIdx.x < s) red[threadIdx.x] += red[threadIdx.x + s];
        __syncthreads();
    }
    if (threadIdx.x == 0) atomicAdd(acc + 1, red[0]);
}

__global__ void idx_out(const int* __restrict__ idx, float* __restrict__ out, int count) {
    int gid = blockIdx.x * 256 + threadIdx.x;
    if (gid < count) out[gid] = (float)idx[gid];
}

__global__ void finalize(const double* __restrict__ acc, float* __restrict__ out,
                         double vq_den, double rec_den) {
    double vq = 1.25 * acc[0] / vq_den;
    double rl = acc[1] / rec_den;
    out[0] = (float)vq;
    out[1] = (float)rl;
    out[2] = (float)(rl + vq);
}

static inline int ceildiv(int a, int b) { return (a + b - 1) / b; }

// ---------------- launch ----------------
extern "C" void kernel_launch(void* const* d_in, const int* in_sizes, int n_in,
                              void* d_out, int out_size, void* d_ws, size_t ws_size,
                              hipStream_t stream) {
    const float* actions = (const float*)d_in[0];
    const float* e_w1 = (const float*)d_in[1];
    const float* e_b1 = (const float*)d_in[2];
    const float* e_w2 = (const float*)d_in[3];
    const float* e_b2 = (const float*)d_in[4];
    const float* e_w3 = (const float*)d_in[5];
    const float* e_b3 = (const float*)d_in[6];
    const float* cb   = (const float*)d_in[7];
    const float* d_w1 = (const float*)d_in[8];
    const float* d_b1 = (const float*)d_in[9];
    const float* d_w2 = (const float*)d_in[10];
    const float* d_b2 = (const float*)d_in[11];
    const float* d_w3 = (const float*)d_in[12];
    const float* d_b3 = (const float*)d_in[13];
    float* out = (float*)d_out;                 // f32 output (confirmed)

    const int FLAT = in_sizes[13];
    const int B    = in_sizes[0] / FLAT;
    const int HID  = in_sizes[2];
    const int LAT  = in_sizes[6];
    const int K    = in_sizes[7] / DD;
    const int NL   = LAT / DD;

    int CHUNK = B < 1024 ? B : 1024;
    auto need = [&](int ch) -> size_t {
        return (size_t)ch * HID * 4 * 2      // h1c,h2c
             + (size_t)ch * LAT * 4 * 2      // latc, Qc
             + (size_t)ch * HID * 4 * 2      // g1c,g2c
             + (size_t)ch * FLAT * 4         // recc
             + (size_t)K * 4 + 64            // t2 + acc
             + (size_t)B * NL * 4;           // idx
    };
    while (CHUNK > 16 && need(CHUNK) > ws_size) CHUNK >>= 1;
    if (need(CHUNK) > ws_size) {
        plant_diag<<<1, 64, 0, stream>>>(2222.0f, out);
        return;
    }
    const int NCHUNK = ceildiv(B, CHUNK);

    char* ws = (char*)d_ws;
    size_t off = 0;
    float* h1c  = (float*)(ws + off); off += (size_t)CHUNK * HID * 4;
    float* h2c  = (float*)(ws + off); off += (size_t)CHUNK * HID * 4;
    float* latc = (float*)(ws + off); off += (size_t)CHUNK * LAT * 4;
    float* Qc   = (float*)(ws + off); off += (size_t)CHUNK * LAT * 4;
    float* g1c  = (float*)(ws + off); off += (size_t)CHUNK * HID * 4;
    float* g2c  = (float*)(ws + off); off += (size_t)CHUNK * HID * 4;
    float* recc = (float*)(ws + off); off += (size_t)CHUNK * FLAT * 4;
    float* t2   = (float*)(ws + off); off += (size_t)K * 4;
    double* acc = (double*)(ws + off); off += 64;
    int*   idx  = (int*)(ws + off);

    zero_acc<<<1, 64, 0, stream>>>(acc);
    code_t2<<<ceildiv(K, 256), 256, 0, stream>>>(cb, t2, K);

    for (int c = 0; c < NCHUNK; ++c) {
        const int r0 = c * CHUNK;
        const int cbR = (B - r0 < CHUNK) ? (B - r0) : CHUNK;
        const float* act_c = actions + (size_t)r0 * FLAT;
        int* idx_c = idx + (size_t)r0 * NL;

        // encoder: np-f32-faithful sequential-FMA chains (bit-identical to round 8)
        gemm_rows<true><<<dim3(ceildiv(HID, 256), ceildiv(cbR, 8)), 256, 0, stream>>>(
            act_c, e_w1, e_b1, h1c, cbR, HID, FLAT);
        gemm_rows<true><<<dim3(ceildiv(HID, 256), ceildiv(cbR, 8)), 256, 0, stream>>>(
            h1c, e_w2, e_b2, h2c, cbR, HID, HID);
        gemm_rows<false><<<dim3(ceildiv(LAT, 256), ceildiv(cbR, 8)), 256, 0, stream>>>(
            h2c, e_w3, e_b3, latc, cbR, LAT, HID);

        // VQ: register-tiled, np-f32 exact
        vq_np2<<<ceildiv(cbR * NL, 64), 256, 0, stream>>>(latc, cb, t2, idx_c, acc, K, cbR * NL);

        // decoder (loose tolerance; same exact kernel is fine and fast)
        q_gather<<<ceildiv(cbR * LAT, 256), 256, 0, stream>>>(idx_c, cb, Qc, cbR * LAT, NL);
        gemm_rows<true><<<dim3(ceildiv(HID, 256), ceildiv(cbR, 8)), 256, 0, stream>>>(
            Qc, d_w1, d_b1, g1c, cbR, HID, LAT);
        gemm_rows<true><<<dim3(ceildiv(HID, 256), ceildiv(cbR, 8)), 256, 0, stream>>>(
            g1c, d_w2, d_b2, g2c, cbR, HID, HID);
        gemm_rows<false><<<dim3(ceildiv(FLAT, 256), ceildiv(cbR, 8)), 256, 0, stream>>>(
            g2c, d_w3, d_b3, recc, cbR, FLAT, HID);

        recon_out<<<ceildiv(cbR * FLAT, 256), 256, 0, stream>>>(
            recc, act_c, out + (size_t)r0 * FLAT, acc, cbR * FLAT);
    }

    // f32 packing: [ recon B*FLAT | indices B*NL | vq, recon_loss, loss ]
    idx_out<<<ceildiv(B * NL, 256), 256, 0, stream>>>(idx, out + (size_t)B * FLAT, B * NL);
    finalize<<<1, 1, 0, stream>>>(acc, out + (size_t)B * FLAT + (size_t)B * NL,
                                  (double)B * NL * DD, (double)B * FLAT);
}